// Round 1
// baseline (415.192 us; speedup 1.0000x reference)
//
#include <hip/hip_runtime.h>
#include <stdint.h>

typedef unsigned long long u64;
typedef unsigned int u32;

#define T_STEPS 100
#define NNEUR 256
#define NBF 2048                 // B*F = 32*64
#define NELEM (NBF * NNEUR)      // 524288 per time step
#define BF_PER_BLOCK 64
#define CHUNKS (NBF / BF_PER_BLOCK)   // 32

// ---- Threefry-2x32, 20 rounds, exactly as jax/_src/prng.py ----
__device__ __forceinline__ void tf2x32(u32 k0, u32 k1, u32& x0, u32& x1) {
  u32 k2 = k0 ^ k1 ^ 0x1BD11BDAu;
  x0 += k0; x1 += k1;
#define TFR(r) { x0 += x1; x1 = (x1 << (r)) | (x1 >> (32 - (r))); x1 ^= x0; }
  TFR(13) TFR(15) TFR(26) TFR(6)
  x0 += k1; x1 += k2 + 1u;
  TFR(17) TFR(29) TFR(16) TFR(24)
  x0 += k2; x1 += k0 + 2u;
  TFR(13) TFR(15) TFR(26) TFR(6)
  x0 += k0; x1 += k1 + 3u;
  TFR(17) TFR(29) TFR(16) TFR(24)
  x0 += k1; x1 += k2 + 4u;
  TFR(13) TFR(15) TFR(26) TFR(6)
  x0 += k2; x1 += k0 + 5u;
#undef TFR
}

// p[bf*256+n] = (expf32(-(d*d)/((2*w)*w)) * adapt) * 0.1f, exp via double (correctly rounded)
__global__ void __launch_bounds__(256) kern_p(
    const float* __restrict__ x, const float* __restrict__ c,
    const float* __restrict__ w, const float* __restrict__ a,
    float* __restrict__ p) {
  int idx = blockIdx.x * 256 + threadIdx.x;
  int n = idx & 255, bf = idx >> 8;
  float d = x[bf] - c[n];
  float denom = (2.0f * w[n]) * w[n];
  float q = -(d * d) / denom;
  float e = (float)exp((double)q);
  p[idx] = (e * a[n]) * 0.1f;
}

// Stage A: threefry bits (JAX partitionable mode: bits = out0 ^ out1 of block (hi=0, lo=i)),
// compare vs p, pack bits, OR-reduce per-(t,n) occurrence masks.
template <bool USE_P>
__global__ void __launch_bounds__(256) kern_bits(
    const float* __restrict__ p,
    const float* __restrict__ x, const float* __restrict__ c,
    const float* __restrict__ w, const float* __restrict__ a,
    const int* __restrict__ seedp,
    u64* __restrict__ cmp64,        // primary: packed compare bits [bf][t][4]
    float* __restrict__ outf,       // fallback: raw 0/1 floats into d_out
    u64* __restrict__ occ64) {      // [t][4] OR-reduced over bf
  const int t = blockIdx.x;
  const int chunk = blockIdx.y;
  const int lane = threadIdx.x & 63;
  const int v = threadIdx.x >> 6;
  const int n = v * 64 + lane;
  const u32 seed = (u32)seedp[0];

  // k_t = fold_in(key(seed), t) = threefry2x32(key=(0,seed), x=(0,t))
  u32 kt0 = 0u, kt1 = (u32)t;
  tf2x32(0u, seed, kt0, kt1);

  float cn = 0.f, wn = 0.f, an = 0.f;
  if (!USE_P) { cn = c[n]; wn = w[n]; an = a[n]; }

  bool occ = false;
#pragma unroll 2
  for (int j = 0; j < BF_PER_BLOCK; ++j) {
    int bf = chunk * BF_PER_BLOCK + j;
    u32 i = (u32)(bf * 256 + n);      // flat index into [B,F,N]
    u32 b0 = 0u, b1 = i;              // 64-bit counter: hi=0, lo=i
    tf2x32(kt0, kt1, b0, b1);
    u32 bits = b0 ^ b1;
    float r = __uint_as_float((bits >> 9) | 0x3F800000u) - 1.0f;
    float pv;
    if (USE_P) {
      pv = p[i];
    } else {
      float d = x[bf] - cn;
      float denom = (2.0f * wn) * wn;
      float q = -(d * d) / denom;
      pv = ((float)exp((double)q) * an) * 0.1f;
    }
    bool cm = r < pv;
    occ |= cm;
    if (USE_P) {
      u64 m = __ballot(cm);
      if (lane == 0) cmp64[((u64)bf * T_STEPS + (u64)t) * 4 + v] = m;
    } else {
      outf[(u64)bf * (NNEUR * T_STEPS) + (u64)n * T_STEPS + t] = cm ? 1.0f : 0.0f;
    }
  }
  u64 om = __ballot(occ);
  if (lane == 0) atomicOr(&occ64[t * 4 + v], om);
}

// Stage B: 100-step refractory recurrence per neuron; emits can_spike bitmasks [t][4]
__global__ void __launch_bounds__(256) kern_rec(
    const float* __restrict__ ref0,
    const u64* __restrict__ occ64,
    u64* __restrict__ can64) {
  int n = threadIdx.x;
  int lane = n & 63, v = n >> 6;
  float ref = ref0[n];
  for (int t = 0; t < T_STEPS; ++t) {
    bool can = (ref == 0.0f);
    u64 cm = __ballot(can);
    if (lane == 0) can64[t * 4 + v] = cm;
    bool occb = (occ64[t * 4 + v] >> lane) & 1ull;
    bool occurred = can && occb;
    ref = fmaxf(ref - 1.0f, 0.0f) + (occurred ? 2.0f : 0.0f);
  }
}

// Stage C (primary): AND cmp-bits with can-bits in LDS, write coalesced float4
__global__ void __launch_bounds__(256) kern_out(
    const u32* __restrict__ cmp32,   // [bf][t][8] 32-bit view
    const u32* __restrict__ can32,   // [t][8]
    float* __restrict__ out) {
  __shared__ u32 s[T_STEPS * 8];
  const int bf = blockIdx.x;
  const int tid = threadIdx.x;
  for (int l = tid; l < T_STEPS * 8; l += 256) {
    int t = l >> 3, ww = l & 7;
    s[l] = cmp32[((u64)bf * T_STEPS + (u64)t) * 8 + ww] & can32[t * 8 + ww];
  }
  __syncthreads();
  float4* outv = (float4*)(out + (u64)bf * (NNEUR * T_STEPS));
#pragma unroll
  for (int k = 0; k < 25; ++k) {
    int q = tid + 256 * k;          // float4 index within slice (6400 total)
    int e = q * 4;
    float4 val;
    float* vp = (float*)&val;
#pragma unroll
    for (int j = 0; j < 4; ++j) {
      int ee = e + j;
      int n = ee / 100;
      int t = ee - n * 100;
      vp[j] = (float)((s[t * 8 + (n >> 5)] >> (n & 31)) & 1u);
    }
    outv[q] = val;
  }
}

// Stage C (fallback): mask raw 0/1 floats already in d_out with can bits
__global__ void __launch_bounds__(256) kern_mask(
    const u32* __restrict__ can32, float* __restrict__ out) {
  u64 q = (u64)blockIdx.x * 256 + threadIdx.x;   // float4 index
  float4* ov = (float4*)out;
  float4 vx = ov[q];
  u32 local = (u32)((q * 4) % (NNEUR * T_STEPS));
  float* vp = (float*)&vx;
#pragma unroll
  for (int j = 0; j < 4; ++j) {
    u32 le = local + j;
    u32 n = le / 100;
    u32 t = le - n * 100;
    u32 bit = (can32[t * 8 + (n >> 5)] >> (n & 31)) & 1u;
    vp[j] = bit ? vp[j] : 0.0f;
  }
  ov[q] = vx;
}

extern "C" void kernel_launch(void* const* d_in, const int* in_sizes, int n_in,
                              void* d_out, int out_size, void* d_ws, size_t ws_size,
                              hipStream_t stream) {
  const float* x  = (const float*)d_in[0];
  const float* c  = (const float*)d_in[1];
  const float* w  = (const float*)d_in[2];
  const float* a  = (const float*)d_in[3];
  const float* r0 = (const float*)d_in[4];
  const int* seed = (const int*)d_in[5];
  float* out = (float*)d_out;

  const size_t P_BYTES   = (size_t)NELEM * 4;                    // 2,097,152
  const size_t CMP_BYTES = (size_t)NBF * T_STEPS * 4 * 8;        // 6,553,600
  const size_t OCC_BYTES = (size_t)T_STEPS * 4 * 8;              // 3,200
  const size_t CAN_BYTES = OCC_BYTES;
  const bool full = ws_size >= P_BYTES + CMP_BYTES + OCC_BYTES + CAN_BYTES;

  uint8_t* wsb = (uint8_t*)d_ws;
  float* p = nullptr; u64* cmp = nullptr; u64* occ; u64* can;
  if (full) {
    p   = (float*)wsb;
    cmp = (u64*)(wsb + P_BYTES);
    occ = (u64*)(wsb + P_BYTES + CMP_BYTES);
    can = (u64*)(wsb + P_BYTES + CMP_BYTES + OCC_BYTES);
  } else {
    occ = (u64*)wsb;
    can = (u64*)(wsb + OCC_BYTES);
  }

  hipMemsetAsync(occ, 0, OCC_BYTES, stream);

  if (full) {
    kern_p<<<NELEM / 256, 256, 0, stream>>>(x, c, w, a, p);
    kern_bits<true><<<dim3(T_STEPS, CHUNKS), 256, 0, stream>>>(
        p, x, c, w, a, seed, cmp, out, occ);
    kern_rec<<<1, 256, 0, stream>>>(r0, occ, can);
    kern_out<<<NBF, 256, 0, stream>>>((const u32*)cmp, (const u32*)can, out);
  } else {
    kern_bits<false><<<dim3(T_STEPS, CHUNKS), 256, 0, stream>>>(
        nullptr, x, c, w, a, seed, nullptr, out, occ);
    kern_rec<<<1, 256, 0, stream>>>(r0, occ, can);
    kern_mask<<<(out_size / 4) / 256, 256, 0, stream>>>((const u32*)can, out);
  }
}

// Round 2
// 363.636 us; speedup vs baseline: 1.1418x; 1.1418x over previous
//
#include <hip/hip_runtime.h>
#include <stdint.h>

typedef unsigned long long u64;
typedef unsigned int u32;

#define T_STEPS 100
#define NNEUR 256
#define NBF 2048                 // B*F = 32*64
#define NELEM (NBF * NNEUR)      // 524288 per time step

// ---- Threefry-2x32, 20 rounds, exactly as jax/_src/prng.py ----
__device__ __forceinline__ void tf2x32(u32 k0, u32 k1, u32& x0, u32& x1) {
  u32 k2 = k0 ^ k1 ^ 0x1BD11BDAu;
  x0 += k0; x1 += k1;
#define TFR(r) { x0 += x1; x1 = (x1 << (r)) | (x1 >> (32 - (r))); x1 ^= x0; }
  TFR(13) TFR(15) TFR(26) TFR(6)
  x0 += k1; x1 += k2 + 1u;
  TFR(17) TFR(29) TFR(16) TFR(24)
  x0 += k2; x1 += k0 + 2u;
  TFR(13) TFR(15) TFR(26) TFR(6)
  x0 += k0; x1 += k1 + 3u;
  TFR(17) TFR(29) TFR(16) TFR(24)
  x0 += k1; x1 += k2 + 4u;
  TFR(13) TFR(15) TFR(26) TFR(6)
  x0 += k2; x1 += k0 + 5u;
#undef TFR
}

__device__ __forceinline__ u32 rotl32(u32 x, int r) {
  // funnel-shift-right(x,x,32-r) == rotl(x,r); guarantees v_alignbit_b32
  return __builtin_amdgcn_alignbit(x, x, 32 - r);
}

// thr[i] = ceil(p_i * 2^23): integer compare threshold for (bits>>9) < thr
__global__ void __launch_bounds__(256) kern_p(
    const float* __restrict__ x, const float* __restrict__ c,
    const float* __restrict__ w, const float* __restrict__ a,
    u32* __restrict__ thr) {
  int idx = blockIdx.x * 256 + threadIdx.x;
  int n = idx & 255, bf = idx >> 8;
  float d = x[bf] - c[n];
  float denom = (2.0f * w[n]) * w[n];
  float q = -(d * d) / denom;
  float e = (float)exp((double)q);
  float p = (e * a[n]) * 0.1f;
  thr[idx] = (u32)ceilf(p * 8388608.0f);   // p*2^23 is exact (pow2 scale)
}

// Stage A: thread owns (bf, octet of 32 neurons); 32 fully-unrolled threefry
// chains, integer-threshold compare, bits packed into one u32; no ballot.
__global__ void __launch_bounds__(256, 8) kern_bits2(
    const u32* __restrict__ thr,
    const int* __restrict__ seedp,
    u32* __restrict__ cmp32,        // [bf][t][8]
    u32* __restrict__ occ32) {      // [t][8] OR-reduced over bf
  const int t = blockIdx.x;
  const int g = blockIdx.y;        // 0..63 (32 bf each)
  const int tid = threadIdx.x;
  const int oct = tid & 7;
  const int bfl = tid >> 3;        // 0..31
  const int bf = g * 32 + bfl;
  const u32 seed = (u32)seedp[0];

  // k_t = fold_in(key(seed), t) = threefry2x32(key=(0,seed), x=(0,t))
  u32 K0 = 0u, K1 = (u32)t;
  tf2x32(0u, seed, K0, K1);
  const u32 K2 = K0 ^ K1 ^ 0x1BD11BDAu;
  const u32 I01 = K1 + 1u + K2;    // pre-fold injection consts (wave-uniform)
  const u32 I10 = K1;
  const u32 I11 = K2 + 1u;
  const u32 I20 = K2;
  const u32 I21 = K0 + 2u;
  const u32 I30 = K0;
  const u32 I31 = K1 + 3u;
  const u32 I40 = K1;
  const u32 I41 = K2 + 4u;
  const u32 I50 = K2;
  const u32 I51 = K0 + 5u;
  (void)I01;

  const u32 base_i = (u32)(bf * 256 + oct * 32);

  // 32 thresholds resident in VGPRs
  u32 th[32];
  const uint4* tp = (const uint4*)(thr + base_i);
#pragma unroll
  for (int q = 0; q < 8; ++q) {
    uint4 v = tp[q];
    th[4*q] = v.x; th[4*q+1] = v.y; th[4*q+2] = v.z; th[4*q+3] = v.w;
  }

  const u32 x1base = base_i + K1;
  u32 word = 0u;
#pragma unroll
  for (int k = 31; k >= 0; --k) {
    u32 x0 = K0;
    u32 x1 = x1base + (u32)k;
#define QR(r) { x0 += x1; x1 = rotl32(x1, r); x1 ^= x0; }
    QR(13) QR(15) QR(26) QR(6)
    x0 += I10; x1 += I11;
    QR(17) QR(29) QR(16) QR(24)
    x0 += I20; x1 += I21;
    QR(13) QR(15) QR(26) QR(6)
    x0 += I30; x1 += I31;
    QR(17) QR(29) QR(16) QR(24)
    x0 += I40; x1 += I41;
    QR(13) QR(15) QR(26) QR(6)
    x0 += I50; x1 += I51;
#undef QR
    u32 m = (x0 ^ x1) >> 9;
    word = (word << 1) | (m < th[k] ? 1u : 0u);
  }

  cmp32[((u32)bf * T_STEPS + (u32)t) * 8 + oct] = word;

  // OR across the 8 bf-values in this wave (lanes differ in bits 3..5)
  u32 o = word;
  o |= (u32)__shfl_xor((int)o, 8, 64);
  o |= (u32)__shfl_xor((int)o, 16, 64);
  o |= (u32)__shfl_xor((int)o, 32, 64);
  if ((tid & 63) < 8) atomicOr(&occ32[t * 8 + oct], o);
}

// Stage B+C fused: per-bf block re-runs the 100-step refractory recurrence
// from occ in LDS, then ANDs cmp bits with can bits and writes float4 output.
__global__ void __launch_bounds__(256) kern_out2(
    const u32* __restrict__ cmp32,   // [bf][t][8]
    const u32* __restrict__ occ32,   // [t][8]
    const float* __restrict__ ref0,
    float* __restrict__ out) {
  __shared__ u32 s_occ[T_STEPS * 8];
  __shared__ u32 s_can[T_STEPS * 8];
  __shared__ u32 s[T_STEPS * 8];
  const int bf = blockIdx.x;
  const int tid = threadIdx.x;

  for (int l = tid; l < T_STEPS * 8; l += 256) s_occ[l] = occ32[l];
  __syncthreads();

  {
    const int n = tid, lane = n & 63, v = n >> 6;
    float ref = ref0[n];
    for (int t = 0; t < T_STEPS; ++t) {
      bool can = (ref == 0.0f);
      u64 cm = __ballot(can);
      if (lane == 0) {
        s_can[t * 8 + v * 2]     = (u32)cm;
        s_can[t * 8 + v * 2 + 1] = (u32)(cm >> 32);
      }
      bool occb = (s_occ[t * 8 + (n >> 5)] >> (n & 31)) & 1u;
      bool occurred = can && occb;
      ref = fmaxf(ref - 1.0f, 0.0f) + (occurred ? 2.0f : 0.0f);
    }
  }
  __syncthreads();

  for (int l = tid; l < T_STEPS * 8; l += 256) {
    int t = l >> 3, ww = l & 7;
    s[l] = cmp32[((u64)bf * T_STEPS + (u64)t) * 8 + ww] & s_can[l];
  }
  __syncthreads();

  float4* outv = (float4*)(out + (u64)bf * (NNEUR * T_STEPS));
#pragma unroll
  for (int kk = 0; kk < 25; ++kk) {
    int q = tid + 256 * kk;          // float4 index within slice (6400 total)
    int e = q * 4;
    float4 val;
    float* vp = (float*)&val;
#pragma unroll
    for (int j = 0; j < 4; ++j) {
      int ee = e + j;
      int n = ee / 100;
      int t = ee - n * 100;
      vp[j] = (float)((s[t * 8 + (n >> 5)] >> (n & 31)) & 1u);
    }
    outv[q] = val;
  }
}

// ---------------- fallback path (ws too small): previous working scheme ----
__global__ void __launch_bounds__(256) kern_bits_fb(
    const float* __restrict__ x, const float* __restrict__ c,
    const float* __restrict__ w, const float* __restrict__ a,
    const int* __restrict__ seedp,
    float* __restrict__ outf,
    u64* __restrict__ occ64) {
  const int t = blockIdx.x;
  const int chunk = blockIdx.y;
  const int lane = threadIdx.x & 63;
  const int v = threadIdx.x >> 6;
  const int n = v * 64 + lane;
  const u32 seed = (u32)seedp[0];
  u32 kt0 = 0u, kt1 = (u32)t;
  tf2x32(0u, seed, kt0, kt1);
  float cn = c[n], wn = w[n], an = a[n];
  bool occ = false;
  for (int j = 0; j < 64; ++j) {
    int bf = chunk * 64 + j;
    u32 i = (u32)(bf * 256 + n);
    u32 b0 = 0u, b1 = i;
    tf2x32(kt0, kt1, b0, b1);
    u32 bits = b0 ^ b1;
    float r = __uint_as_float((bits >> 9) | 0x3F800000u) - 1.0f;
    float d = x[bf] - cn;
    float denom = (2.0f * wn) * wn;
    float q = -(d * d) / denom;
    float pv = ((float)exp((double)q) * an) * 0.1f;
    bool cm = r < pv;
    occ |= cm;
    outf[(u64)bf * (NNEUR * T_STEPS) + (u64)n * T_STEPS + t] = cm ? 1.0f : 0.0f;
  }
  u64 om = __ballot(occ);
  if (lane == 0) atomicOr(&occ64[t * 4 + v], om);
}

__global__ void __launch_bounds__(256) kern_rec(
    const float* __restrict__ ref0,
    const u64* __restrict__ occ64,
    u64* __restrict__ can64) {
  int n = threadIdx.x;
  int lane = n & 63, v = n >> 6;
  float ref = ref0[n];
  for (int t = 0; t < T_STEPS; ++t) {
    bool can = (ref == 0.0f);
    u64 cm = __ballot(can);
    if (lane == 0) can64[t * 4 + v] = cm;
    bool occb = (occ64[t * 4 + v] >> lane) & 1ull;
    bool occurred = can && occb;
    ref = fmaxf(ref - 1.0f, 0.0f) + (occurred ? 2.0f : 0.0f);
  }
}

__global__ void __launch_bounds__(256) kern_mask(
    const u32* __restrict__ can32, float* __restrict__ out) {
  u64 q = (u64)blockIdx.x * 256 + threadIdx.x;
  float4* ov = (float4*)out;
  float4 vx = ov[q];
  u32 local = (u32)((q * 4) % (NNEUR * T_STEPS));
  float* vp = (float*)&vx;
#pragma unroll
  for (int j = 0; j < 4; ++j) {
    u32 le = local + j;
    u32 n = le / 100;
    u32 t = le - n * 100;
    u32 bit = (can32[t * 8 + (n >> 5)] >> (n & 31)) & 1u;
    vp[j] = bit ? vp[j] : 0.0f;
  }
  ov[q] = vx;
}

extern "C" void kernel_launch(void* const* d_in, const int* in_sizes, int n_in,
                              void* d_out, int out_size, void* d_ws, size_t ws_size,
                              hipStream_t stream) {
  const float* x  = (const float*)d_in[0];
  const float* c  = (const float*)d_in[1];
  const float* w  = (const float*)d_in[2];
  const float* a  = (const float*)d_in[3];
  const float* r0 = (const float*)d_in[4];
  const int* seed = (const int*)d_in[5];
  float* out = (float*)d_out;

  const size_t P_BYTES   = (size_t)NELEM * 4;                    // 2 MB thresholds
  const size_t CMP_BYTES = (size_t)NBF * T_STEPS * 4 * 8;        // 6.55 MB
  const size_t OCC_BYTES = (size_t)T_STEPS * 4 * 8;              // 3200 B
  const bool full = ws_size >= P_BYTES + CMP_BYTES + 2 * OCC_BYTES;

  uint8_t* wsb = (uint8_t*)d_ws;

  if (full) {
    u32* thr   = (u32*)wsb;
    u32* cmp   = (u32*)(wsb + P_BYTES);
    u32* occ   = (u32*)(wsb + P_BYTES + CMP_BYTES);
    hipMemsetAsync(occ, 0, OCC_BYTES, stream);
    kern_p<<<NELEM / 256, 256, 0, stream>>>(x, c, w, a, thr);
    kern_bits2<<<dim3(T_STEPS, 64), 256, 0, stream>>>(thr, seed, cmp, occ);
    kern_out2<<<NBF, 256, 0, stream>>>(cmp, occ, r0, out);
  } else {
    u64* occ = (u64*)wsb;
    u64* can = (u64*)(wsb + OCC_BYTES);
    hipMemsetAsync(occ, 0, OCC_BYTES, stream);
    kern_bits_fb<<<dim3(T_STEPS, 32), 256, 0, stream>>>(x, c, w, a, seed, out, occ);
    kern_rec<<<1, 256, 0, stream>>>(r0, occ, can);
    kern_mask<<<(out_size / 4) / 256, 256, 0, stream>>>((const u32*)can, out);
  }
}